// Round 1
// baseline (7552.670 us; speedup 1.0000x reference)
//
#include <hip/hip_runtime.h>

#define IN_F 256
#define OUT_F 128

// ---------------------------------------------------------------------------
// K1: out[i*128+j] = bias[j]  (float4-vectorized), and zero deg[]
// ---------------------------------------------------------------------------
__global__ __launch_bounds__(256) void init_kernel(float* __restrict__ out,
                                                   const float* __restrict__ bias,
                                                   int* __restrict__ deg,
                                                   int n_nodes) {
    int i = blockIdx.x * 256 + threadIdx.x;
    int total4 = n_nodes * (OUT_F / 4);
    if (i < total4) {
        const float4* b4 = reinterpret_cast<const float4*>(bias);
        reinterpret_cast<float4*>(out)[i] = b4[i & (OUT_F / 4 - 1)];
    }
    if (i < n_nodes) deg[i] = 0;
}

// ---------------------------------------------------------------------------
// K2: deg[dst[e]] += 1
// ---------------------------------------------------------------------------
__global__ __launch_bounds__(256) void deg_kernel(const int* __restrict__ dst,
                                                  int* __restrict__ deg,
                                                  int n_edges) {
    int i = blockIdx.x * 256 + threadIdx.x;
    if (i < n_edges) atomicAdd(&deg[dst[i]], 1);
}

// ---------------------------------------------------------------------------
// K3: norm[i] = 1/sqrt(max(deg,1))
// ---------------------------------------------------------------------------
__global__ __launch_bounds__(256) void norm_kernel(const int* __restrict__ deg,
                                                   float* __restrict__ norm,
                                                   int n_nodes) {
    int i = blockIdx.x * 256 + threadIdx.x;
    if (i < n_nodes) {
        float d = (float)deg[i];
        if (d < 1.0f) d = 1.0f;
        norm[i] = 1.0f / sqrtf(d);
    }
}

// ---------------------------------------------------------------------------
// K4: h = (feat * norm[row]) @ W    (M=n_nodes, K=256, N=128, all f32)
// BM=32 rows/block, full N=128, BK=32. 256 threads, 4x4 micro-tile per thread.
// ---------------------------------------------------------------------------
#define BM 32
#define BK 32

__global__ __launch_bounds__(256) void gemm_kernel(const float* __restrict__ feat,
                                                   const float* __restrict__ W,
                                                   const float* __restrict__ norm,
                                                   float* __restrict__ h,
                                                   int n_nodes) {
    __shared__ float As[BM][BK];        // 4 KB
    __shared__ float Bs[BK][OUT_F];     // 16 KB

    const int tid = threadIdx.x;
    const int block_row = blockIdx.x * BM;
    const int tcol = (tid & 31) * 4;    // 0..124
    const int trow = (tid >> 5) * 4;    // 0..28

    float acc[4][4] = {};

    for (int k0 = 0; k0 < IN_F; k0 += BK) {
        // --- load A tile (32x32): one float4 per thread ---
        {
            int r = tid >> 3;           // 0..31
            int c = (tid & 7) * 4;      // 0..28
            int grow = block_row + r;
            float4 v = make_float4(0.f, 0.f, 0.f, 0.f);
            if (grow < n_nodes) {
                v = *reinterpret_cast<const float4*>(&feat[grow * IN_F + k0 + c]);
                float nm = norm[grow];
                v.x *= nm; v.y *= nm; v.z *= nm; v.w *= nm;
            }
            *reinterpret_cast<float4*>(&As[r][c]) = v;
        }
        // --- load B tile (32x128): four float4 per thread ---
        {
            #pragma unroll
            for (int t = 0; t < 4; ++t) {
                int idx = tid + t * 256;       // 0..1023 (float4 index)
                int r = idx >> 5;              // 0..31
                int c = (idx & 31) * 4;        // 0..124
                *reinterpret_cast<float4*>(&Bs[r][c]) =
                    *reinterpret_cast<const float4*>(&W[(k0 + r) * OUT_F + c]);
            }
        }
        __syncthreads();

        // --- FMA: 4 rows x 4 cols per thread over BK ---
        #pragma unroll
        for (int kk4 = 0; kk4 < BK; kk4 += 4) {
            float4 a[4];
            #pragma unroll
            for (int i = 0; i < 4; ++i)
                a[i] = *reinterpret_cast<const float4*>(&As[trow + i][kk4]);
            #pragma unroll
            for (int t = 0; t < 4; ++t) {
                float4 b = *reinterpret_cast<const float4*>(&Bs[kk4 + t][tcol]);
                #pragma unroll
                for (int i = 0; i < 4; ++i) {
                    float av = (t == 0) ? a[i].x : (t == 1) ? a[i].y : (t == 2) ? a[i].z : a[i].w;
                    acc[i][0] += av * b.x;
                    acc[i][1] += av * b.y;
                    acc[i][2] += av * b.z;
                    acc[i][3] += av * b.w;
                }
            }
        }
        __syncthreads();
    }

    #pragma unroll
    for (int i = 0; i < 4; ++i) {
        int grow = block_row + trow + i;
        if (grow < n_nodes) {
            float4 v = make_float4(acc[i][0], acc[i][1], acc[i][2], acc[i][3]);
            *reinterpret_cast<float4*>(&h[grow * OUT_F + tcol]) = v;
        }
    }
}

// ---------------------------------------------------------------------------
// K5: out[dst[e]] += norm[dst[e]] * h[src[e]]   (8 edges/block, 32 lanes/edge)
// ---------------------------------------------------------------------------
__global__ __launch_bounds__(256) void scatter_kernel(const float* __restrict__ h,
                                                      const int* __restrict__ src,
                                                      const int* __restrict__ dst,
                                                      const float* __restrict__ norm,
                                                      float* __restrict__ out,
                                                      int n_edges) {
    int lane = threadIdx.x & 31;          // feature group: 4 floats each
    int esub = threadIdx.x >> 5;          // 0..7
    int e = blockIdx.x * 8 + esub;
    if (e >= n_edges) return;

    int s = src[e];
    int d = dst[e];
    float nd = norm[d];
    float4 v = *reinterpret_cast<const float4*>(&h[s * OUT_F + lane * 4]);
    float* o = &out[d * OUT_F + lane * 4];
    atomicAdd(o + 0, v.x * nd);
    atomicAdd(o + 1, v.y * nd);
    atomicAdd(o + 2, v.z * nd);
    atomicAdd(o + 3, v.w * nd);
}

// ---------------------------------------------------------------------------
extern "C" void kernel_launch(void* const* d_in, const int* in_sizes, int n_in,
                              void* d_out, int out_size, void* d_ws, size_t ws_size,
                              hipStream_t stream) {
    const float* feat   = (const float*)d_in[0];
    const float* weight = (const float*)d_in[1];
    const float* bias   = (const float*)d_in[2];
    const int*   src    = (const int*)d_in[3];
    const int*   dst    = (const int*)d_in[4];
    float* out = (float*)d_out;

    const int n_nodes = in_sizes[0] / IN_F;
    const int n_edges = in_sizes[3];

    // workspace layout: h (n_nodes*128 f32) | norm (n_nodes f32) | deg (n_nodes i32)
    char* ws = (char*)d_ws;
    float* h    = (float*)ws;
    float* norm = (float*)(ws + (size_t)n_nodes * OUT_F * sizeof(float));
    int*   deg  = (int*)(ws + (size_t)n_nodes * OUT_F * sizeof(float) + (size_t)n_nodes * sizeof(float));

    // K1: out = bias broadcast; deg = 0
    {
        int total4 = n_nodes * (OUT_F / 4);
        int blocks = (total4 + 255) / 256;
        init_kernel<<<blocks, 256, 0, stream>>>(out, bias, deg, n_nodes);
    }
    // K2: degree count
    {
        int blocks = (n_edges + 255) / 256;
        deg_kernel<<<blocks, 256, 0, stream>>>(dst, deg, n_edges);
    }
    // K3: norm
    {
        int blocks = (n_nodes + 255) / 256;
        norm_kernel<<<blocks, 256, 0, stream>>>(deg, norm, n_nodes);
    }
    // K4: h = (feat*norm) @ W
    {
        int blocks = (n_nodes + BM - 1) / BM;
        gemm_kernel<<<blocks, 256, 0, stream>>>(feat, weight, norm, h, n_nodes);
    }
    // K5: scatter-add into out
    {
        int blocks = (n_edges + 7) / 8;
        scatter_kernel<<<blocks, 256, 0, stream>>>(h, src, dst, norm, out, n_edges);
    }
}

// Round 2
// 5708.165 us; speedup vs baseline: 1.3231x; 1.3231x over previous
//
#include <hip/hip_runtime.h>

#define IN_F 256
#define OUT_F 128

typedef short bf16x8 __attribute__((ext_vector_type(8)));
typedef float f32x4 __attribute__((ext_vector_type(4)));
typedef unsigned short us8 __attribute__((ext_vector_type(8)));

__device__ inline unsigned short f2bf(float x) {
    union { float f; unsigned u; } v; v.f = x;
    unsigned r = v.u + 0x7FFFu + ((v.u >> 16) & 1u);   // round-nearest-even
    return (unsigned short)(r >> 16);
}
__device__ inline float bf2f(unsigned short x) {
    union { unsigned u; float f; } v; v.u = ((unsigned)x) << 16;
    return v.f;
}

// ---------------------------------------------------------------------------
// K1: out[i*128+j] = bias[j]  (float4-vectorized), and zero deg[]
// ---------------------------------------------------------------------------
__global__ __launch_bounds__(256) void init_kernel(float* __restrict__ out,
                                                   const float* __restrict__ bias,
                                                   int* __restrict__ deg,
                                                   int n_nodes) {
    int i = blockIdx.x * 256 + threadIdx.x;
    int total4 = n_nodes * (OUT_F / 4);
    if (i < total4) {
        const float4* b4 = reinterpret_cast<const float4*>(bias);
        reinterpret_cast<float4*>(out)[i] = b4[i & (OUT_F / 4 - 1)];
    }
    if (i < n_nodes) deg[i] = 0;
}

// ---------------------------------------------------------------------------
// K2: deg[dst[e]] += 1
// ---------------------------------------------------------------------------
__global__ __launch_bounds__(256) void deg_kernel(const int* __restrict__ dst,
                                                  int* __restrict__ deg,
                                                  int n_edges) {
    int i = blockIdx.x * 256 + threadIdx.x;
    if (i < n_edges) atomicAdd(&deg[dst[i]], 1);
}

// ---------------------------------------------------------------------------
// K3: norm[i] = 1/sqrt(max(deg,1))
// ---------------------------------------------------------------------------
__global__ __launch_bounds__(256) void norm_kernel(const int* __restrict__ deg,
                                                   float* __restrict__ norm,
                                                   int n_nodes) {
    int i = blockIdx.x * 256 + threadIdx.x;
    if (i < n_nodes) {
        float d = (float)deg[i];
        if (d < 1.0f) d = 1.0f;
        norm[i] = 1.0f / sqrtf(d);
    }
}

// ---------------------------------------------------------------------------
// K4: W[256][128] f32  ->  Wt[128][256] bf16   (transpose + convert, 128 KB)
// ---------------------------------------------------------------------------
__global__ __launch_bounds__(256) void wprep_kernel(const float* __restrict__ W,
                                                    unsigned short* __restrict__ Wt) {
    int n = blockIdx.x;      // 0..127 (output row = W column)
    int k = threadIdx.x;     // 0..255
    Wt[n * IN_F + k] = f2bf(W[k * OUT_F + n]);
}

// ---------------------------------------------------------------------------
// K5: h = bf16( (feat * norm[row]) @ W )  via MFMA 16x16x32 bf16, LDS-free.
// 4 waves/block, each wave owns 16 rows x all 128 cols. K=256 in 8 steps.
// A frag: lane l -> row (l&15), k = (l>>4)*8 + j  (two float4 loads, scale, cvt)
// B frag: lane l -> col (l&15), k = (l>>4)*8 + j  (one 16B load from Wt[N][K])
// C/D   : col = lane&15, row = (lane>>4)*4 + reg   [m89-verified]
// ---------------------------------------------------------------------------
__global__ __launch_bounds__(256) void gemm_mfma(const float* __restrict__ feat,
                                                 const unsigned short* __restrict__ Wt,
                                                 const float* __restrict__ norm,
                                                 unsigned short* __restrict__ h,
                                                 int n_nodes) {
    const int wave = threadIdx.x >> 6;
    const int lane = threadIdx.x & 63;
    const int r0   = (blockIdx.x * 4 + wave) * 16;
    const int lrow = lane & 15;
    const int kgrp = (lane >> 4) * 8;

    const int row    = r0 + lrow;
    const bool rvalid = row < n_nodes;
    const int rowc   = rvalid ? row : (n_nodes - 1);       // clamp, nm=0 masks
    const float nm   = rvalid ? norm[rowc] : 0.0f;
    const float* arow = feat + (size_t)rowc * IN_F;

    f32x4 acc[8];
    #pragma unroll
    for (int n = 0; n < 8; ++n) acc[n] = (f32x4){0.f, 0.f, 0.f, 0.f};

    #pragma unroll
    for (int k0 = 0; k0 < IN_F / 32; ++k0) {
        float4 a0 = *reinterpret_cast<const float4*>(arow + k0 * 32 + kgrp);
        float4 a1 = *reinterpret_cast<const float4*>(arow + k0 * 32 + kgrp + 4);
        bf16x8 afr;
        afr[0] = (short)f2bf(a0.x * nm);
        afr[1] = (short)f2bf(a0.y * nm);
        afr[2] = (short)f2bf(a0.z * nm);
        afr[3] = (short)f2bf(a0.w * nm);
        afr[4] = (short)f2bf(a1.x * nm);
        afr[5] = (short)f2bf(a1.y * nm);
        afr[6] = (short)f2bf(a1.z * nm);
        afr[7] = (short)f2bf(a1.w * nm);
        #pragma unroll
        for (int n = 0; n < 8; ++n) {
            bf16x8 bfr = *reinterpret_cast<const bf16x8*>(
                Wt + (size_t)(n * 16 + lrow) * IN_F + k0 * 32 + kgrp);
            acc[n] = __builtin_amdgcn_mfma_f32_16x16x32_bf16(afr, bfr, acc[n], 0, 0, 0);
        }
    }

    const int orow0 = r0 + (lane >> 4) * 4;
    #pragma unroll
    for (int n = 0; n < 8; ++n) {
        #pragma unroll
        for (int j = 0; j < 4; ++j) {
            int orow = orow0 + j;
            if (orow < n_nodes)
                h[(size_t)orow * OUT_F + n * 16 + lrow] = f2bf(acc[n][j]);
        }
    }
}

// ---------------------------------------------------------------------------
// K6: out[dst[e]] += norm[dst[e]] * h_bf16[src[e]]   (16 lanes/edge, 8 f32/lane)
// ---------------------------------------------------------------------------
__global__ __launch_bounds__(256) void scatter_kernel(const unsigned short* __restrict__ h,
                                                      const int* __restrict__ src,
                                                      const int* __restrict__ dst,
                                                      const float* __restrict__ norm,
                                                      float* __restrict__ out,
                                                      int n_edges) {
    int l16 = threadIdx.x & 15;
    int e = blockIdx.x * 16 + (threadIdx.x >> 4);
    if (e >= n_edges) return;

    int s = src[e];
    int d = dst[e];
    float nd = norm[d];
    us8 v = *reinterpret_cast<const us8*>(h + (size_t)s * OUT_F + l16 * 8);
    float* o = out + (size_t)d * OUT_F + l16 * 8;
    #pragma unroll
    for (int j = 0; j < 8; ++j)
        atomicAdd(o + j, bf2f(v[j]) * nd);
}

// ---------------------------------------------------------------------------
extern "C" void kernel_launch(void* const* d_in, const int* in_sizes, int n_in,
                              void* d_out, int out_size, void* d_ws, size_t ws_size,
                              hipStream_t stream) {
    const float* feat   = (const float*)d_in[0];
    const float* weight = (const float*)d_in[1];
    const float* bias   = (const float*)d_in[2];
    const int*   src    = (const int*)d_in[3];
    const int*   dst    = (const int*)d_in[4];
    float* out = (float*)d_out;

    const int n_nodes = in_sizes[0] / IN_F;
    const int n_edges = in_sizes[3];

    // ws layout: h_bf16 (n*128 us) | norm (n f32) | deg (n i32) | Wt (128*256 us)
    char* ws = (char*)d_ws;
    size_t off = 0;
    unsigned short* h = (unsigned short*)(ws + off); off += (size_t)n_nodes * OUT_F * sizeof(unsigned short);
    float* norm       = (float*)(ws + off);          off += (size_t)n_nodes * sizeof(float);
    int*   deg        = (int*)(ws + off);            off += (size_t)n_nodes * sizeof(int);
    unsigned short* Wt = (unsigned short*)(ws + off);

    // K1: out = bias broadcast; deg = 0
    {
        int total4 = n_nodes * (OUT_F / 4);
        init_kernel<<<(total4 + 255) / 256, 256, 0, stream>>>(out, bias, deg, n_nodes);
    }
    // K2: degree count
    deg_kernel<<<(n_edges + 255) / 256, 256, 0, stream>>>(dst, deg, n_edges);
    // K3: norm
    norm_kernel<<<(n_nodes + 255) / 256, 256, 0, stream>>>(deg, norm, n_nodes);
    // K4: Wt = bf16(W^T)
    wprep_kernel<<<OUT_F, IN_F, 0, stream>>>(weight, Wt);
    // K5: h = bf16((feat*norm) @ W)
    {
        int blocks = (n_nodes + 63) / 64;   // 64 rows per block (4 waves x 16)
        gemm_mfma<<<blocks, 256, 0, stream>>>(feat, Wt, norm, h, n_nodes);
    }
    // K6: scatter-add into out
    scatter_kernel<<<(n_edges + 15) / 16, 256, 0, stream>>>(h, src, dst, norm, out, n_edges);
}

// Round 3
// 351.418 us; speedup vs baseline: 21.4920x; 16.2432x over previous
//
#include <hip/hip_runtime.h>

#define IN_F 256
#define OUT_F 128

typedef short bf16x8 __attribute__((ext_vector_type(8)));
typedef float f32x4 __attribute__((ext_vector_type(4)));

__device__ inline unsigned short f2bf(float x) {
    union { float f; unsigned u; } v; v.f = x;
    unsigned r = v.u + 0x7FFFu + ((v.u >> 16) & 1u);   // round-nearest-even
    return (unsigned short)(r >> 16);
}
__device__ inline float bf2f(unsigned short x) {
    union { unsigned u; float f; } v; v.u = ((unsigned)x) << 16;
    return v.f;
}

// ---------------------------------------------------------------------------
// zero deg[] and cursor[]
// ---------------------------------------------------------------------------
__global__ __launch_bounds__(256) void zero_kernel(int* __restrict__ deg,
                                                   int* __restrict__ cursor,
                                                   int n_nodes) {
    int i = blockIdx.x * 256 + threadIdx.x;
    if (i < n_nodes) { deg[i] = 0; cursor[i] = 0; }
}

// ---------------------------------------------------------------------------
// deg[dst[e]] += 1
// ---------------------------------------------------------------------------
__global__ __launch_bounds__(256) void deg_kernel(const int* __restrict__ dst,
                                                  int* __restrict__ deg,
                                                  int n_edges) {
    int i = blockIdx.x * 256 + threadIdx.x;
    if (i < n_edges) atomicAdd(&deg[dst[i]], 1);
}

// ---------------------------------------------------------------------------
// norm[i] = 1/sqrt(max(deg,1))
// ---------------------------------------------------------------------------
__global__ __launch_bounds__(256) void norm_kernel(const int* __restrict__ deg,
                                                   float* __restrict__ norm,
                                                   int n_nodes) {
    int i = blockIdx.x * 256 + threadIdx.x;
    if (i < n_nodes) {
        float d = (float)deg[i];
        if (d < 1.0f) d = 1.0f;
        norm[i] = 1.0f / sqrtf(d);
    }
}

// ---------------------------------------------------------------------------
// Exclusive scan of deg -> rstart.  3 kernels, 1024 elems/block.
// ---------------------------------------------------------------------------
__global__ __launch_bounds__(256) void scan1_kernel(const int* __restrict__ deg,
                                                    int* __restrict__ rstart,
                                                    int* __restrict__ bsum,
                                                    int n) {
    __shared__ int sh[256];
    const int tid = threadIdx.x;
    const int base = blockIdx.x * 1024;
    int v[4], s = 0;
    #pragma unroll
    for (int j = 0; j < 4; ++j) {
        int idx = base + tid * 4 + j;
        v[j] = (idx < n) ? deg[idx] : 0;
        s += v[j];
    }
    sh[tid] = s;
    __syncthreads();
    #pragma unroll
    for (int off = 1; off < 256; off <<= 1) {
        int t = (tid >= off) ? sh[tid - off] : 0;
        __syncthreads();
        sh[tid] += t;
        __syncthreads();
    }
    int ex = sh[tid] - s;
    #pragma unroll
    for (int j = 0; j < 4; ++j) {
        int idx = base + tid * 4 + j;
        if (idx < n) rstart[idx] = ex;
        ex += v[j];
    }
    if (tid == 255) bsum[blockIdx.x] = sh[255];
}

__global__ __launch_bounds__(256) void scan2_kernel(int* __restrict__ bsum, int nb) {
    __shared__ int sh[256];
    const int tid = threadIdx.x;
    int v[4], s = 0;
    #pragma unroll
    for (int j = 0; j < 4; ++j) {
        int idx = tid * 4 + j;
        v[j] = (idx < nb) ? bsum[idx] : 0;
        s += v[j];
    }
    sh[tid] = s;
    __syncthreads();
    #pragma unroll
    for (int off = 1; off < 256; off <<= 1) {
        int t = (tid >= off) ? sh[tid - off] : 0;
        __syncthreads();
        sh[tid] += t;
        __syncthreads();
    }
    int ex = sh[tid] - s;
    #pragma unroll
    for (int j = 0; j < 4; ++j) {
        int idx = tid * 4 + j;
        if (idx < nb) { int old = v[j]; bsum[idx] = ex; ex += old; }
    }
}

__global__ __launch_bounds__(256) void scan3_kernel(int* __restrict__ rstart,
                                                    const int* __restrict__ bsum,
                                                    int n) {
    int i = blockIdx.x * 256 + threadIdx.x;
    if (i < n) rstart[i] += bsum[i >> 10];
}

// ---------------------------------------------------------------------------
// CSR fill: eidx[rstart[d] + cursor[d]++] = src[e]
// ---------------------------------------------------------------------------
__global__ __launch_bounds__(256) void fill_kernel(const int* __restrict__ src,
                                                   const int* __restrict__ dst,
                                                   const int* __restrict__ rstart,
                                                   int* __restrict__ cursor,
                                                   int* __restrict__ eidx,
                                                   int n_edges) {
    int e = blockIdx.x * 256 + threadIdx.x;
    if (e < n_edges) {
        int d = dst[e];
        int pos = atomicAdd(&cursor[d], 1);
        eidx[rstart[d] + pos] = src[e];
    }
}

// ---------------------------------------------------------------------------
// W[256][128] f32 -> Wt[128][256] bf16
// ---------------------------------------------------------------------------
__global__ __launch_bounds__(256) void wprep_kernel(const float* __restrict__ W,
                                                    unsigned short* __restrict__ Wt) {
    int n = blockIdx.x;
    int k = threadIdx.x;
    Wt[n * IN_F + k] = f2bf(W[k * OUT_F + n]);
}

// ---------------------------------------------------------------------------
// h = bf16( (feat * norm[row]) @ W )  via MFMA 16x16x32 bf16, LDS-free.
// ---------------------------------------------------------------------------
__global__ __launch_bounds__(256) void gemm_mfma(const float* __restrict__ feat,
                                                 const unsigned short* __restrict__ Wt,
                                                 const float* __restrict__ norm,
                                                 unsigned short* __restrict__ h,
                                                 int n_nodes) {
    const int wave = threadIdx.x >> 6;
    const int lane = threadIdx.x & 63;
    const int r0   = (blockIdx.x * 4 + wave) * 16;
    const int lrow = lane & 15;
    const int kgrp = (lane >> 4) * 8;

    const int row    = r0 + lrow;
    const bool rvalid = row < n_nodes;
    const int rowc   = rvalid ? row : (n_nodes - 1);
    const float nm   = rvalid ? norm[rowc] : 0.0f;
    const float* arow = feat + (size_t)rowc * IN_F;

    f32x4 acc[8];
    #pragma unroll
    for (int n = 0; n < 8; ++n) acc[n] = (f32x4){0.f, 0.f, 0.f, 0.f};

    #pragma unroll
    for (int k0 = 0; k0 < IN_F / 32; ++k0) {
        float4 a0 = *reinterpret_cast<const float4*>(arow + k0 * 32 + kgrp);
        float4 a1 = *reinterpret_cast<const float4*>(arow + k0 * 32 + kgrp + 4);
        bf16x8 afr;
        afr[0] = (short)f2bf(a0.x * nm);
        afr[1] = (short)f2bf(a0.y * nm);
        afr[2] = (short)f2bf(a0.z * nm);
        afr[3] = (short)f2bf(a0.w * nm);
        afr[4] = (short)f2bf(a1.x * nm);
        afr[5] = (short)f2bf(a1.y * nm);
        afr[6] = (short)f2bf(a1.z * nm);
        afr[7] = (short)f2bf(a1.w * nm);
        #pragma unroll
        for (int n = 0; n < 8; ++n) {
            bf16x8 bfr = *reinterpret_cast<const bf16x8*>(
                Wt + (size_t)(n * 16 + lrow) * IN_F + k0 * 32 + kgrp);
            acc[n] = __builtin_amdgcn_mfma_f32_16x16x32_bf16(afr, bfr, acc[n], 0, 0, 0);
        }
    }

    const int orow0 = r0 + (lane >> 4) * 4;
    #pragma unroll
    for (int n = 0; n < 8; ++n) {
        #pragma unroll
        for (int j = 0; j < 4; ++j) {
            int orow = orow0 + j;
            if (orow < n_nodes)
                h[(size_t)orow * OUT_F + n * 16 + lrow] = f2bf(acc[n][j]);
        }
    }
}

// ---------------------------------------------------------------------------
// Aggregate: one wave per dst node. Gather h[src] rows (64 lanes x 4B = 256B
// coalesced per edge), sum in f32 regs, write out = agg*norm + bias once.
// ---------------------------------------------------------------------------
__global__ __launch_bounds__(256) void agg_kernel(const unsigned short* __restrict__ h,
                                                  const int* __restrict__ eidx,
                                                  const int* __restrict__ rstart,
                                                  const int* __restrict__ deg,
                                                  const float* __restrict__ norm,
                                                  const float* __restrict__ bias,
                                                  float* __restrict__ out,
                                                  int n_nodes) {
    const int wave = threadIdx.x >> 6;
    const int lane = threadIdx.x & 63;
    const int node = blockIdx.x * 4 + wave;
    if (node >= n_nodes) return;

    const int start = rstart[node];
    const int cnt   = deg[node];

    float a0 = 0.f, a1 = 0.f;
    int i = 0;
    for (; i + 2 <= cnt; i += 2) {
        int s0 = eidx[start + i];
        int s1 = eidx[start + i + 1];
        unsigned v0 = *reinterpret_cast<const unsigned*>(h + (size_t)s0 * OUT_F + lane * 2);
        unsigned v1 = *reinterpret_cast<const unsigned*>(h + (size_t)s1 * OUT_F + lane * 2);
        a0 += bf2f((unsigned short)(v0 & 0xffffu)) + bf2f((unsigned short)(v1 & 0xffffu));
        a1 += bf2f((unsigned short)(v0 >> 16))     + bf2f((unsigned short)(v1 >> 16));
    }
    if (i < cnt) {
        int s0 = eidx[start + i];
        unsigned v0 = *reinterpret_cast<const unsigned*>(h + (size_t)s0 * OUT_F + lane * 2);
        a0 += bf2f((unsigned short)(v0 & 0xffffu));
        a1 += bf2f((unsigned short)(v0 >> 16));
    }

    const float nm = norm[node];
    float2 r;
    r.x = a0 * nm + bias[lane * 2];
    r.y = a1 * nm + bias[lane * 2 + 1];
    *reinterpret_cast<float2*>(out + (size_t)node * OUT_F + lane * 2) = r;
}

// ---------------------------------------------------------------------------
extern "C" void kernel_launch(void* const* d_in, const int* in_sizes, int n_in,
                              void* d_out, int out_size, void* d_ws, size_t ws_size,
                              hipStream_t stream) {
    const float* feat   = (const float*)d_in[0];
    const float* weight = (const float*)d_in[1];
    const float* bias   = (const float*)d_in[2];
    const int*   src    = (const int*)d_in[3];
    const int*   dst    = (const int*)d_in[4];
    float* out = (float*)d_out;

    const int n_nodes = in_sizes[0] / IN_F;
    const int n_edges = in_sizes[3];

    // ws layout
    char* ws = (char*)d_ws;
    size_t off = 0;
    unsigned short* h  = (unsigned short*)(ws + off); off += (size_t)n_nodes * OUT_F * sizeof(unsigned short);
    float* norm        = (float*)(ws + off);          off += (size_t)n_nodes * sizeof(float);
    int*   deg         = (int*)(ws + off);            off += (size_t)n_nodes * sizeof(int);
    int*   rstart      = (int*)(ws + off);            off += (size_t)n_nodes * sizeof(int);
    int*   cursor      = (int*)(ws + off);            off += (size_t)n_nodes * sizeof(int);
    int*   bsum        = (int*)(ws + off);            off += 1024 * sizeof(int);
    unsigned short* Wt = (unsigned short*)(ws + off); off += (size_t)OUT_F * IN_F * sizeof(unsigned short);
    int*   eidx        = (int*)(ws + off);            off += (size_t)n_edges * sizeof(int);

    const int nb = (n_nodes + 1023) / 1024;

    zero_kernel<<<(n_nodes + 255) / 256, 256, 0, stream>>>(deg, cursor, n_nodes);
    deg_kernel<<<(n_edges + 255) / 256, 256, 0, stream>>>(dst, deg, n_edges);
    norm_kernel<<<(n_nodes + 255) / 256, 256, 0, stream>>>(deg, norm, n_nodes);
    scan1_kernel<<<nb, 256, 0, stream>>>(deg, rstart, bsum, n_nodes);
    scan2_kernel<<<1, 256, 0, stream>>>(bsum, nb);
    scan3_kernel<<<(n_nodes + 255) / 256, 256, 0, stream>>>(rstart, bsum, n_nodes);
    fill_kernel<<<(n_edges + 255) / 256, 256, 0, stream>>>(src, dst, rstart, cursor, eidx, n_edges);
    wprep_kernel<<<OUT_F, IN_F, 0, stream>>>(weight, Wt);
    gemm_mfma<<<(n_nodes + 63) / 64, 256, 0, stream>>>(feat, Wt, norm, h, n_nodes);
    agg_kernel<<<(n_nodes + 3) / 4, 256, 0, stream>>>(h, eidx, rstart, deg, norm, bias, out, n_nodes);
}